// Round 4
// baseline (628.722 us; speedup 1.0000x reference)
//
#include <hip/hip_runtime.h>
#include <hip/hip_bf16.h>
#include <stdint.h>

#define T_DIM 512
#define IN_DIM 4096
#define OUT_DIM 11008

typedef __attribute__((ext_vector_type(8))) __bf16 bf16x8;
typedef __attribute__((ext_vector_type(8))) short shortx8;
typedef __attribute__((ext_vector_type(4))) float f32x4;
typedef __attribute__((ext_vector_type(4))) int intx4;

__device__ __forceinline__ short f32_to_bf16_bits(float f) {
    uint32_t x = __builtin_bit_cast(uint32_t, f);
    x += 0x7FFFu + ((x >> 16) & 1u);   // RTNE; inputs are finite
    return (short)(x >> 16);
}

// ---- quantize activations: xq = sf_decode(sf_encode(x)), stored as bf16 ----
__global__ __launch_bounds__(256) void encode_x_kernel(const float* __restrict__ x,
                                                       short* __restrict__ xq) {
    const float MAXV = 2047.0f / 2048.0f;
    int i = (blockIdx.x * 256 + threadIdx.x) * 8;
    float4 a = *(const float4*)(x + i);
    float4 b = *(const float4*)(x + i + 4);
    float v[8] = {a.x, a.y, a.z, a.w, b.x, b.y, b.z, b.w};
    union { short s[8]; intx4 v4; } u;
#pragma unroll
    for (int j = 0; j < 8; ++j) {
        float xv = v[j];
        float ax = fminf(fabsf(xv), MAXV);
        float m = floorf(ax * 2047.0f / MAXV);   // faithful two-step rounding
        // reference sign convention: (2*sign-1) -> +1 when x<0, -1 otherwise
        float q = m * (1.0f / 2048.0f) * (xv < 0.0f ? 1.0f : -1.0f);
        u.s[j] = f32_to_bf16_bits(q);
    }
    *(intx4*)(xq + i) = u.v4;
}

// ---- fused: decode B from enc/mask/wf in-kernel, GEMM, scale+bias epilogue ----
// C[512,11008] = (xq[512,4096] @ decode(enc)[11008,4096]^T) * scale[col] + bias
#define BM 128
#define BN 64
#define BK 32
#define BNP 40   // padded Bs row stride (elems): uniform bank spread for ds ops
#define KITERS (IN_DIM / BK)

__global__ __launch_bounds__(256) void fused_gemm_kernel(const short* __restrict__ A,
                                                         const int* __restrict__ enc,
                                                         const int* __restrict__ mask,
                                                         const float* __restrict__ wf,
                                                         const float* __restrict__ scale,
                                                         const float* __restrict__ bias,
                                                         float* __restrict__ C) {
    __shared__ short As[BM * BK];    // 8 KB, unpadded (global_load_lds layout)
    __shared__ short Bs[BN * BNP];   // 5 KB, padded
    const int tid  = threadIdx.x;
    const int wave = tid >> 6;
    const int lane = tid & 63;
    const int bm = blockIdx.x;   // fastest dim: 4 blocks sharing bn run adjacent
    const int bn = blockIdx.y;

    // A staging (lds-dma): flat bf16 elem f = (it*256+tid)*8 in [128][32] tile
    const int f0 = tid * 8;
    const int r0 = f0 >> 5, c0 = f0 & 31;
    const int f1 = (256 + tid) * 8;
    const int r1 = f1 >> 5, c1 = f1 & 31;
    const short* gA0 = A + (size_t)(bm * BM + r0) * IN_DIM + c0;
    const short* gA1 = A + (size_t)(bm * BM + r1) * IN_DIM + c1;
    short* lA0 = As + (wave * 64) * 8;          // wave-uniform base + lane*16B
    short* lA1 = As + (256 + wave * 64) * 8;

    // B decode coords: thread covers 8 consecutive k at row rB
    const int rB = tid >> 2;            // 0..63 (n-row within tile)
    const int cB = (tid & 3) * 8;       // k-offset 0/8/16/24
    const size_t goff = (size_t)(bn * BN + rB) * IN_DIM + cB;
    const int* encp = enc + goff;
    const int* mskp = mask + goff;
    const float* wfp = wf + goff;
    short* sB = Bs + rB * BNP + cB;     // per-thread ds_write addr, 16B aligned

    const int wm = (wave >> 1) * 64;
    const int wn = (wave & 1) * 32;
    const int quad = lane >> 4;
    const int lr   = lane & 15;

    f32x4 acc[4][2] = {};

    // prologue: loads for kt=0
    intx4 e0 = *(const intx4*)(encp);
    intx4 e1 = *(const intx4*)(encp + 4);
    intx4 m0 = *(const intx4*)(mskp);
    intx4 m1 = *(const intx4*)(mskp + 4);

    for (int kt = 0; kt < KITERS; ++kt) {
        const int ko = kt * BK;
        // A tile -> LDS via DMA
        __builtin_amdgcn_global_load_lds((__attribute__((address_space(1))) void*)(gA0 + ko),
                                         (__attribute__((address_space(3))) void*)lA0, 16, 0, 0);
        __builtin_amdgcn_global_load_lds((__attribute__((address_space(1))) void*)(gA1 + ko),
                                         (__attribute__((address_space(3))) void*)lA1, 16, 0, 0);
        // decode this iter's B elems from prefetched regs
        int ev[8] = {e0.x, e0.y, e0.z, e0.w, e1.x, e1.y, e1.z, e1.w};
        int mk[8] = {m0.x, m0.y, m0.z, m0.w, m1.x, m1.y, m1.z, m1.w};
        union { short s[8]; intx4 v4; } u;
#pragma unroll
        for (int j = 0; j < 8; ++j) {
            int v12 = ev[j];
            // sf_decode: mantissa/2048; sign bit set -> +1, clear -> -1 (faithful)
            float v = (float)(v12 & 2047) * (1.0f / 2048.0f) * (((v12 >> 11) & 1) ? 1.0f : -1.0f);
            if (mk[j]) v = wfp[ko + j];   // exec-masked, ~0.5% of lanes
            u.s[j] = f32_to_bf16_bits(v);
        }
        *(intx4*)sB = u.v4;
        __syncthreads();   // drains lds-dma (vmcnt) + ds_write (lgkmcnt)

        // prefetch next iter's enc/mask (overlaps frag reads + MFMA)
        if (kt + 1 < KITERS) {
            const int kn = ko + BK;
            e0 = *(const intx4*)(encp + kn);
            e1 = *(const intx4*)(encp + kn + 4);
            m0 = *(const intx4*)(mskp + kn);
            m1 = *(const intx4*)(mskp + kn + 4);
        }

        bf16x8 af[4], bfr[2];
#pragma unroll
        for (int mi = 0; mi < 4; ++mi)
            af[mi] = __builtin_bit_cast(bf16x8,
                *(const shortx8*)(As + (wm + mi * 16 + lr) * BK + quad * 8));
#pragma unroll
        for (int ni = 0; ni < 2; ++ni)
            bfr[ni] = __builtin_bit_cast(bf16x8,
                *(const shortx8*)(Bs + (wn + ni * 16 + lr) * BNP + quad * 8));
#pragma unroll
        for (int mi = 0; mi < 4; ++mi)
#pragma unroll
            for (int ni = 0; ni < 2; ++ni)
                acc[mi][ni] = __builtin_amdgcn_mfma_f32_16x16x32_bf16(
                    af[mi], bfr[ni], acc[mi][ni], 0, 0, 0);
        __syncthreads();   // all LDS reads done before next staging overwrite
    }

    // epilogue: C/D layout col=lane&15, row=quad*4+reg; scale folded here
    const int rowb = bm * BM + wm + quad * 4;
    const int colb = bn * BN + wn + lr;
#pragma unroll
    for (int ni = 0; ni < 2; ++ni) {
        const int col = colb + ni * 16;
        const float sv = scale[col];
        const float bv = bias[col];
#pragma unroll
        for (int mi = 0; mi < 4; ++mi) {
#pragma unroll
            for (int r = 0; r < 4; ++r) {
                const int row = rowb + mi * 16 + r;
                C[(size_t)row * OUT_DIM + col] = acc[mi][ni][r] * sv + bv;
            }
        }
    }
}

extern "C" void kernel_launch(void* const* d_in, const int* in_sizes, int n_in,
                              void* d_out, int out_size, void* d_ws, size_t ws_size,
                              hipStream_t stream) {
    const float* x     = (const float*)d_in[0];   // [512,4096]
    const float* wf    = (const float*)d_in[1];   // [11008,4096]
    const float* scale = (const float*)d_in[2];   // [11008]
    const float* bias  = (const float*)d_in[3];   // [11008]
    const int*   enc   = (const int*)d_in[4];     // [11008,4096]
    const int*   mask  = (const int*)d_in[5];     // [11008,4096] (bool -> int32)
    float* out = (float*)d_out;

    short* xq = (short*)d_ws;   // 512*4096 bf16 = 4 MB

    encode_x_kernel<<<(T_DIM * IN_DIM) / (256 * 8), 256, 0, stream>>>(x, xq);
    dim3 grid(T_DIM / BM, OUT_DIM / BN);   // (4, 172): bm fastest for L3 sharing
    fused_gemm_kernel<<<grid, 256, 0, stream>>>(xq, enc, mask, wf, scale, bias, out);
}